// Round 5
// baseline (204.506 us; speedup 1.0000x reference)
//
#include <hip/hip_runtime.h>
#include <stdint.h>

typedef __attribute__((ext_vector_type(8))) short short8;
typedef __attribute__((ext_vector_type(4))) float f32x4;
typedef __attribute__((ext_vector_type(4))) unsigned int u32x4;
typedef __attribute__((ext_vector_type(2))) unsigned int u32x2;

// Skeleton (fixed in reference)
__constant__ int NBRC[17][4] = {
    {7, 1, 4, 0}, {0, 2, 0, 0}, {1, 3, 0, 0}, {2, 0, 0, 0},
    {0, 5, 0, 0}, {4, 6, 0, 0}, {5, 0, 0, 0}, {0, 8, 0, 0},
    {7, 9, 11, 14}, {8, 10, 0, 0}, {9, 0, 0, 0}, {8, 12, 0, 0},
    {11, 13, 0, 0}, {12, 0, 0, 0}, {8, 15, 0, 0}, {14, 16, 0, 0},
    {15, 0, 0, 0}};
__constant__ int DEGC[17] = {3,2,2,1,2,2,1,2,4,2,1,2,2,1,2,2,1};
__constant__ float RDEGC[5] = {0.f, 1.f, 0.5f, 0.33333334f, 0.25f};
// packed joint meta: nb0|nb1<<5|nb2<<10|nb3<<15|deg<<20
#define PKJ_(a,b,c,d,g) ((uint32_t)(a) | ((uint32_t)(b)<<5) | ((uint32_t)(c)<<10) | ((uint32_t)(d)<<15) | ((uint32_t)(g)<<20))
__constant__ uint32_t PKJ[17] = {
    PKJ_(7,1,4,0,3),  PKJ_(0,2,0,0,2),  PKJ_(1,3,0,0,2),  PKJ_(2,0,0,0,1),
    PKJ_(0,5,0,0,2),  PKJ_(4,6,0,0,2),  PKJ_(5,0,0,0,1),  PKJ_(0,8,0,0,2),
    PKJ_(7,9,11,14,4),PKJ_(8,10,0,0,2), PKJ_(9,0,0,0,1),  PKJ_(8,12,0,0,2),
    PKJ_(11,13,0,0,2),PKJ_(12,0,0,0,1), PKJ_(8,15,0,0,2), PKJ_(14,16,0,0,2),
    PKJ_(15,0,0,0,1)};
// per-wave output-joint-tile assignment, balanced so sum(deg) = 8 per wave
__constant__ int WNT[4] = {3, 4, 5, 5};
__constant__ int WJT[4][5] = {{8, 1, 2, 0, 0},
                              {0, 4, 5, 3, 0},
                              {7, 9, 11, 6, 10},
                              {12, 14, 15, 13, 16}};

__device__ inline unsigned short f2bf(float f) {
  union { float f; uint32_t u; } v; v.f = f;
  uint32_t u = v.u;
  uint32_t r = u + 0x7fffu + ((u >> 16) & 1u);  // RNE
  return (unsigned short)(r >> 16);
}
__device__ inline uint32_t pk2(float a, float b) {
  return (uint32_t)f2bf(a) | ((uint32_t)f2bf(b) << 16);
}
__device__ inline float rdeg(int d) {
  return (d == 1) ? 1.f : (d == 2) ? 0.5f : (d == 3) ? 0.33333334f : 0.25f;
}
__device__ inline f32x4 mfma16(short8 a, short8 b, f32x4 c) {
  return __builtin_amdgcn_mfma_f32_16x16x32_bf16(a, b, c, 0, 0, 0);
}

// ---------------- prep kernel (unchanged from r4) ----------------
__global__ void prep(const float* __restrict__ W1,
                     const float* __restrict__ W2,
                     const float* __restrict__ Wp2,
                     const float* __restrict__ W3,
                     const float* __restrict__ Wp1,
                     const float* __restrict__ b3,
                     const float* __restrict__ bp1,
                     short* __restrict__ W1b,
                     short* __restrict__ W2b,
                     short* __restrict__ Wp2b,
                     short* __restrict__ Mb,
                     float* __restrict__ bp1p) {
  __shared__ float w3s[4096];
  __shared__ float Qs[256];
  const int tid = threadIdx.x;
  const int bx = blockIdx.x;
  if (bx < 272) {
    for (int q = tid; q < 4096; q += 256) w3s[q] = W3[q];
    {
      int ro = tid >> 6, k = tid & 63;
      int r = bx * 4 + ro;
      int f = r / 17, i = r - f * 17;
      int dj = DEGC[i];
      float s = 0.f;
#pragma unroll
      for (int t = 0; t < 4; t++) {
        if (t < dj) {
          int nb = NBRC[i][t];
          s += RDEGC[DEGC[nb]] * Wp1[f * 1088 + nb * 64 + k];
        }
      }
      Qs[ro * 64 + k] = s;
    }
    __syncthreads();
    {
      int ro = tid >> 6, c = tid & 63;
      int r = bx * 4 + ro;
      int f = r / 17, i = r - f * 17;
      float s = 0.f;
#pragma unroll
      for (int k = 0; k < 64; k++) s += Qs[ro * 64 + k] * w3s[k * 64 + c];
      int col = i * 64 + c;
      int kk = col >> 5, qq = (col >> 3) & 3, cb = col & 7;
      int w = f >> 4, l15 = f & 15;
      Mb[(((w * 34 + kk) * 64) + qq * 16 + l15) * 8 + cb] = (short)f2bf(s);
    }
  } else if (bx < 354) {
    int q = (bx - 272) * 256 + tid;
    if (q < 4096) W2b[q] = (short)f2bf(W2[q]);
    int q2 = q - 4096;
    if (q2 >= 0 && q2 < 16384) Wp2b[q2] = (short)f2bf(Wp2[q2]);
    int q3 = q - 20480;
    if (q3 >= 0 && q3 < 512) {
      int k = q3 & 7;
      W1b[q3] = (k < 3) ? (short)f2bf(W1[(q3 >> 3) * 3 + k]) : (short)0;
    }
  } else {
    int wv = tid >> 6, l = tid & 63;
    int f = (bx - 354) * 4 + wv;
    float s = 0.f;
#pragma unroll
    for (int i = 0; i < 17; i++) s += Wp1[f * 1088 + i * 64 + l] * b3[l];
#pragma unroll
    for (int off = 32; off > 0; off >>= 1) s += __shfl_down(s, off);
    if (l == 0) bp1p[f] = bp1[f] + s;
  }
}

// ---------------- main fused kernel ----------------
// 16 elements/block, 256 threads, 4 blocks/CU. Row = joint*16 + elem, stride 72.
// LDS = 39680 B: hbuf (h-activations; aliases xraw early, zb late) + sbias.
__launch_bounds__(256, 4)
__global__ void gcn_main(const float* __restrict__ X,
                         const short* __restrict__ Mb,
                         const short* __restrict__ Wp2b,
                         const short* __restrict__ W2b,
                         const short* __restrict__ W1b,
                         const float* __restrict__ bp1p,
                         const float* __restrict__ b1g,
                         const float* __restrict__ b2g,
                         const float* __restrict__ bp2g,
                         float* __restrict__ OUT) {
  __shared__ __align__(16) short hbuf[272 * 72];  // 39168 B
  __shared__ __align__(16) float sbias[128];      // b1|b2

  const int tid = threadIdx.x;
  const int wave = tid >> 6;
  const int lane = tid & 63;
  const int ln15 = lane & 15;
  const int quad = lane >> 4;
  const int e0 = blockIdx.x * 16;

  // ---- init ----
  float* xraw = (float*)hbuf;  // 816 floats, transient (dead at barrier B)
  if (tid < 204) ((f32x4*)xraw)[tid] = ((const f32x4*)(X + e0 * 51))[tid];
  short8 w1f[4];
#pragma unroll
  for (int ft = 0; ft < 4; ft++)
    w1f[ft] = *(const short8*)(W1b + (ft * 16 + ln15) * 8);
  f32x4 bp1v = *(const f32x4*)&bp1p[wave * 16 + quad * 4];  // held for pool epilogue
  if (tid < 128) sbias[tid] = (tid < 64) ? b1g[tid] : b2g[tid - 64];
  __syncthreads();  // A: xraw/sbias ready

  auto wb = [&](f32x4 c, int j, int ft, int bofs, float scale) {
    int r = j * 16 + ln15;
    int fb = ft * 16 + quad * 4;
    f32x4 bv = *(const f32x4*)&sbias[bofs + fb];
    float v0 = fmaxf(c.x * scale + bv.x, 0.f);
    float v1 = fmaxf(c.y * scale + bv.y, 0.f);
    float v2 = fmaxf(c.z * scale + bv.z, 0.f);
    float v3 = fmaxf(c.w * scale + bv.w, 0.f);
    u32x2 pk;
    pk.x = pk2(v0, v1);
    pk.y = pk2(v2, v3);
    *(u32x2*)&hbuf[r * 72 + fb] = pk;
  };

  const int nt = WNT[wave];
  f32x4 acc[5][4];

  // ---- agg0 (registers, quad-0 lanes) + Layer 1 MFMAs ----
  {
    short8 bfr[5];
#pragma unroll
    for (int t = 0; t < 5; t++) {
      union { short8 s; u32x4 u; } fr;
      fr.u = (u32x4){0u, 0u, 0u, 0u};
      if (t < nt && quad == 0) {
        int j = WJT[wave][t];
        uint32_t pk = PKJ[j];
        int deg = (int)(pk >> 20);
        float s0 = 0.f, s1 = 0.f, s2 = 0.f;
#pragma unroll
        for (int s = 0; s < 4; s++) {
          if (s < deg) {
            int nb = (int)((pk >> (5 * s)) & 31u);
            int b = ln15 * 51 + nb * 3;
            s0 += xraw[b]; s1 += xraw[b + 1]; s2 += xraw[b + 2];
          }
        }
        float w = rdeg(deg);
        fr.u.x = pk2(s0 * w, s1 * w);
        fr.u.y = pk2(s2 * w, 0.f);
      }
      bfr[t] = fr.s;
    }
#pragma unroll
    for (int t = 0; t < 5; t++)
      if (t < nt)
#pragma unroll
        for (int ft = 0; ft < 4; ft++) {
          f32x4 z = (f32x4){0.f, 0.f, 0.f, 0.f};
          acc[t][ft] = mfma16(w1f[ft], bfr[t], z);
        }
  }
  __syncthreads();  // B: all xraw reads done -> hbuf writable
#pragma unroll
  for (int t = 0; t < 5; t++)
    if (t < nt)
#pragma unroll
      for (int ft = 0; ft < 4; ft++) wb(acc[t][ft], WJT[wave][t], ft, 0, 1.f);
  __syncthreads();  // C: h1 ready

  // ---- Layer 2: block-sparse MFMA aggregation; W2 frags from global ----
  {
    short8 w2f[2][4];
#pragma unroll
    for (int kk = 0; kk < 2; kk++)
#pragma unroll
      for (int ft = 0; ft < 4; ft++)
        w2f[kk][ft] = *(const short8*)(W2b + (ft * 16 + ln15) * 64 + kk * 32 + quad * 8);
#pragma unroll
    for (int t = 0; t < 5; t++) {
      if (t < nt) {
#pragma unroll
        for (int ft = 0; ft < 4; ft++) acc[t][ft] = (f32x4){0.f, 0.f, 0.f, 0.f};
        int j = WJT[wave][t];
        uint32_t pk = PKJ[j];
        int deg = (int)(pk >> 20);
#pragma unroll
        for (int s = 0; s < 4; s++) {
          if (s < deg) {
            int i = (int)((pk >> (5 * s)) & 31u);
#pragma unroll
            for (int kk = 0; kk < 2; kk++) {
              short8 bf = *(const short8*)&hbuf[(i * 16 + ln15) * 72 + kk * 32 + quad * 8];
#pragma unroll
              for (int ft = 0; ft < 4; ft++)
                acc[t][ft] = mfma16(w2f[kk][ft], bf, acc[t][ft]);
            }
          }
        }
      }
    }
  }
  __syncthreads();  // D: all h1 reads done
#pragma unroll
  for (int t = 0; t < 5; t++)
    if (t < nt) {
      int j = WJT[wave][t];
      float w = rdeg((int)(PKJ[j] >> 20));
#pragma unroll
      for (int ft = 0; ft < 4; ft++) wb(acc[t][ft], j, ft, 64, w);
    }
  // Mb ring prefetch issues here; latency spans barrier E
  const short8* mrow = ((const short8*)Mb) + (size_t)wave * 34 * 64 + lane;
  short8 pf[8];
#pragma unroll
  for (int p = 0; p < 8; p++) pf[p] = mrow[p * 64];
  __syncthreads();  // E: h2 ready

  // ---- Pool (folded layer3+pool1), swizzled Mb + register ring ----
  f32x4 zc;
  {
    f32x4 accA = (f32x4){0.f, 0.f, 0.f, 0.f};
    f32x4 accB = (f32x4){0.f, 0.f, 0.f, 0.f};
#pragma unroll
    for (int kk = 0; kk < 34; kk++) {
      short8 af = pf[kk & 7];
      if (kk + 8 < 34) pf[kk & 7] = mrow[(kk + 8) * 64];
      int i = kk >> 1;
      int c = (kk & 1) * 32 + quad * 8;
      short8 bf = *(const short8*)&hbuf[(i * 16 + ln15) * 72 + c];
      if (kk & 1) accB = mfma16(af, bf, accB);
      else accA = mfma16(af, bf, accA);
    }
    zc = accA + accB;
  }
  // Wp2 fragment prefetch; latency hides behind barriers F/G
  short8 wp2f[4][2];
#pragma unroll
  for (int t = 0; t < 4; t++) {
    int ot = wave + 4 * t;
    wp2f[t][0] = *(const short8*)(Wp2b + (ot * 16 + ln15) * 64 + quad * 8);
    wp2f[t][1] = *(const short8*)(Wp2b + (ot * 16 + ln15) * 64 + 32 + quad * 8);
  }
  __syncthreads();  // F: all pool hbuf reads done -> rows 0..15 reusable as zb
  {
    int fb = wave * 16 + quad * 4;
    float v0 = fmaxf(zc.x + bp1v.x, 0.f);
    float v1 = fmaxf(zc.y + bp1v.y, 0.f);
    float v2 = fmaxf(zc.z + bp1v.z, 0.f);
    float v3 = fmaxf(zc.w + bp1v.w, 0.f);
    u32x2 pk;
    pk.x = pk2(v0, v1);
    pk.y = pk2(v2, v3);
    *(u32x2*)&hbuf[ln15 * 72 + fb] = pk;  // zb aliased into hbuf rows 0..15
  }
  __syncthreads();  // G: z ready

  // ---- Pool layer 2: out = Wp2 * z + bp2 ----
  {
    short8 bf0 = *(const short8*)&hbuf[ln15 * 72 + quad * 8];
    short8 bf1 = *(const short8*)&hbuf[ln15 * 72 + 32 + quad * 8];
#pragma unroll
    for (int t = 0; t < 4; t++) {
      int ot = wave + 4 * t;
      f32x4 a = (f32x4){0.f, 0.f, 0.f, 0.f};
      a = mfma16(wp2f[t][0], bf0, a);
      a = mfma16(wp2f[t][1], bf1, a);
      int ob = ot * 16 + quad * 4;
      f32x4 bv = *(const f32x4*)&bp2g[ob];
      f32x4 res = a + bv;
      *(f32x4*)(OUT + (size_t)(e0 + ln15) * 256 + ob) = res;
    }
  }
}

extern "C" void kernel_launch(void* const* d_in, const int* in_sizes, int n_in,
                              void* d_out, int out_size, void* d_ws, size_t ws_size,
                              hipStream_t stream) {
  const float* X = (const float*)d_in[0];
  const float* W1 = (const float*)d_in[2];
  const float* b1 = (const float*)d_in[3];
  const float* W2 = (const float*)d_in[4];
  const float* b2 = (const float*)d_in[5];
  const float* W3 = (const float*)d_in[6];
  const float* b3 = (const float*)d_in[7];
  const float* Wp1 = (const float*)d_in[8];
  const float* bp1 = (const float*)d_in[9];
  const float* Wp2 = (const float*)d_in[10];
  const float* bp2 = (const float*)d_in[11];
  float* OUT = (float*)d_out;
  const int B = in_sizes[0] / 51;

  char* ws = (char*)d_ws;
  short* Mb = (short*)(ws + 0);          // 139264 (swizzled)
  short* Wp2b = (short*)(ws + 139264);   // 32768
  short* W2b = (short*)(ws + 172032);    // 8192
  short* W1b = (short*)(ws + 180224);    // 1024
  float* bp1p = (float*)(ws + 181248);   // 256

  prep<<<370, 256, 0, stream>>>(W1, W2, Wp2, W3, Wp1, b3, bp1,
                                W1b, W2b, Wp2b, Mb, bp1p);
  gcn_main<<<B / 16, 256, 0, stream>>>(X, Mb, Wp2b, W2b, W1b, bp1p,
                                       b1, b2, bp2, OUT);
}